// Round 1
// baseline (199.149 us; speedup 1.0000x reference)
//
#include <hip/hip_runtime.h>
#include <hip/hip_bf16.h>

typedef __attribute__((ext_vector_type(8))) short short8;
typedef __attribute__((ext_vector_type(4))) float f32x4;

#define NPERB   110592          // 48^3 points per batch
#define NTOTAL  221184          // B=2
#define WSTRIDE 72              // LDS row stride (bf16 elems) for W tiles
#define HSTRIDE 72              // LDS row stride (bf16 elems) for h-transpose

// float -> bf16 bits, round-to-nearest-even
static __device__ __forceinline__ unsigned short f2bf(float f) {
    unsigned u = __builtin_bit_cast(unsigned, f);
    u += 0x7fffu + ((u >> 16) & 1u);
    return (unsigned short)(u >> 16);
}

__global__ __launch_bounds__(256) void liquid_ode_kernel(
    const float* __restrict__ coords,
    const float* __restrict__ Wh,   const float* __restrict__ Uh,   const float* __restrict__ bh,
    const float* __restrict__ Wtau, const float* __restrict__ Utau, const float* __restrict__ btau,
    const float* __restrict__ Wout, const float* __restrict__ bout,
    float* __restrict__ out)
{
    __shared__ __align__(16) unsigned short wt_lds[64 * WSTRIDE];
    __shared__ __align__(16) unsigned short wh_lds[64 * WSTRIDE];
    __shared__ __align__(16) unsigned short hT[4][16 * HSTRIDE];

    const int tid = threadIdx.x;

    // ---- stage W_tau / W_h into LDS as bf16, row-major with padded stride ----
    for (int i = tid; i < 4096; i += 256) {
        const int g = i >> 6, k = i & 63;
        wt_lds[g * WSTRIDE + k] = f2bf(Wtau[i]);
        wh_lds[g * WSTRIDE + k] = f2bf(Wh[i]);
    }
    __syncthreads();

    const int wid  = tid >> 6;
    const int lane = tid & 63;
    const int p    = lane & 15;   // point within wave tile (= MFMA col)
    const int G    = lane >> 4;   // lane group

    const int wave_global = blockIdx.x * 4 + wid;
    const int nf = wave_global * 16 + p;          // flat point over B*N
    const int b  = nf / NPERB;
    const int n  = nf - b * NPERB;

    const float cx = coords[nf * 3 + 0];
    const float cy = coords[nf * 3 + 1];
    const float cz = coords[nf * 3 + 2];

    // D-layout per-lane state: element (mt, r) <-> g = 16*mt + 4*G + r, point p
    float ut[4][4], uh[4][4], hs[4][4];
    #pragma unroll
    for (int mt = 0; mt < 4; ++mt) {
        #pragma unroll
        for (int r = 0; r < 4; ++r) {
            const int g = 16 * mt + 4 * G + r;
            ut[mt][r] = btau[g] + Utau[g*3+0]*cx + Utau[g*3+1]*cy + Utau[g*3+2]*cz;
            uh[mt][r] = bh[g]   + Uh[g*3+0]*cx   + Uh[g*3+1]*cy   + Uh[g*3+2]*cz;
            hs[mt][r] = 0.0f;
        }
    }

    unsigned short* myhT = hT[wid];

    #pragma unroll 1
    for (int s = 0; s < 8; ++s) {
        // ---- write h (bf16) into wave-local transpose buffer, layout [p][g] ----
        #pragma unroll
        for (int mt = 0; mt < 4; ++mt) {
            uint2 v;
            v.x = (unsigned)f2bf(hs[mt][0]) | ((unsigned)f2bf(hs[mt][1]) << 16);
            v.y = (unsigned)f2bf(hs[mt][2]) | ((unsigned)f2bf(hs[mt][3]) << 16);
            *reinterpret_cast<uint2*>(&myhT[p * HSTRIDE + 16 * mt + 4 * G]) = v;
        }
        // ---- read MFMA B-fragments: lane holds h[k = 32*kt + 8*G + j][p] ----
        // (same-wave producer/consumer: compiler inserts lgkmcnt, no barrier)
        const short8 bf0 = *reinterpret_cast<const short8*>(&myhT[p * HSTRIDE + 8 * G]);
        const short8 bf1 = *reinterpret_cast<const short8*>(&myhT[p * HSTRIDE + 32 + 8 * G]);

        #pragma unroll
        for (int mt = 0; mt < 4; ++mt) {
            const int wrow = (16 * mt + p) * WSTRIDE + 8 * G;   // A-frag: W[16mt+p][8G + j + 32kt]
            const short8 wt0 = *reinterpret_cast<const short8*>(&wt_lds[wrow]);
            const short8 wt1 = *reinterpret_cast<const short8*>(&wt_lds[wrow + 32]);
            const short8 wh0 = *reinterpret_cast<const short8*>(&wh_lds[wrow]);
            const short8 wh1 = *reinterpret_cast<const short8*>(&wh_lds[wrow + 32]);

            f32x4 at = { ut[mt][0], ut[mt][1], ut[mt][2], ut[mt][3] };  // bias via C-init
            f32x4 af = { uh[mt][0], uh[mt][1], uh[mt][2], uh[mt][3] };
            at = __builtin_amdgcn_mfma_f32_16x16x32_bf16(wt0, bf0, at, 0, 0, 0);
            at = __builtin_amdgcn_mfma_f32_16x16x32_bf16(wt1, bf1, at, 0, 0, 0);
            af = __builtin_amdgcn_mfma_f32_16x16x32_bf16(wh0, bf0, af, 0, 0, 0);
            af = __builtin_amdgcn_mfma_f32_16x16x32_bf16(wh1, bf1, af, 0, 0, 0);

            #pragma unroll
            for (int r = 0; r < 4; ++r) {
                float traw = fminf(fmaxf(at[r], -50.0f), 50.0f);
                float sp   = __logf(1.0f + __expf(traw));            // softplus
                float tau  = fmaxf(fmaf(sp, 9.9f, 0.1f), 1e-6f);
                float rtau = __builtin_amdgcn_rcpf(tau);
                float e    = __expf(-af[r]);                          // sigmoid
                float sg   = __builtin_amdgcn_rcpf(1.0f + e);
                float h    = hs[mt][r];
                hs[mt][r]  = fmaf(0.125f, fmaf(-h, rtau, sg), h);     // Euler update
            }
        }
    }

    // ---- fp32 readout: v[o] = tanh(W_out[o]·h + b_out[o]) * 10 ----
    float p0 = 0.0f, p1 = 0.0f, p2 = 0.0f;
    #pragma unroll
    for (int mt = 0; mt < 4; ++mt) {
        #pragma unroll
        for (int r = 0; r < 4; ++r) {
            const int g = 16 * mt + 4 * G + r;
            const float h = hs[mt][r];
            p0 = fmaf(Wout[g],       h, p0);
            p1 = fmaf(Wout[64 + g],  h, p1);
            p2 = fmaf(Wout[128 + g], h, p2);
        }
    }
    p0 += __shfl_xor(p0, 16); p0 += __shfl_xor(p0, 32);
    p1 += __shfl_xor(p1, 16); p1 += __shfl_xor(p1, 32);
    p2 += __shfl_xor(p2, 16); p2 += __shfl_xor(p2, 32);

    if (G < 3) {
        float zz = (G == 0) ? p0 : (G == 1 ? p1 : p2);
        zz += bout[G];
        const float e2 = __expf(2.0f * zz);                       // tanh via exp
        const float t  = 1.0f - 2.0f * __builtin_amdgcn_rcpf(e2 + 1.0f);
        out[(b * 3 + G) * NPERB + n] = t * 10.0f;
    }
}

extern "C" void kernel_launch(void* const* d_in, const int* in_sizes, int n_in,
                              void* d_out, int out_size, void* d_ws, size_t ws_size,
                              hipStream_t stream) {
    const float* coords = (const float*)d_in[0];
    const float* Wh     = (const float*)d_in[1];
    const float* Uh     = (const float*)d_in[2];
    const float* bh     = (const float*)d_in[3];
    const float* Wtau   = (const float*)d_in[4];
    const float* Utau   = (const float*)d_in[5];
    const float* btau   = (const float*)d_in[6];
    const float* Wout   = (const float*)d_in[7];
    const float* bout   = (const float*)d_in[8];
    float* out = (float*)d_out;

    // 221184 points / (4 waves * 16 points) = 3456 blocks of 256 threads
    liquid_ode_kernel<<<dim3(NTOTAL / 64), dim3(256), 0, stream>>>(
        coords, Wh, Uh, bh, Wtau, Utau, btau, Wout, bout, out);
}